// Round 4
// baseline (1223.554 us; speedup 1.0000x reference)
//
#include <hip/hip_runtime.h>
#include <stdint.h>
#include <stddef.h>

// ---- problem constants ----
#define NWIN   64
#define NTOK   64
#define CDIM   192
constexpr float SCALE = 0.17677669529663687f;  // 32^-0.5

typedef float    f32x4 __attribute__((ext_vector_type(4)));
typedef __bf16   bfx8  __attribute__((ext_vector_type(8)));
typedef __bf16   bfx4  __attribute__((ext_vector_type(4)));
typedef uint32_t u32;

union PAu { u32 w[4]; bfx8 v; };

static __device__ __forceinline__ bfx8 pack8(f32x4 a, f32x4 b) {
  bfx8 r;
  r[0] = (__bf16)a[0]; r[1] = (__bf16)a[1]; r[2] = (__bf16)a[2]; r[3] = (__bf16)a[3];
  r[4] = (__bf16)b[0]; r[5] = (__bf16)b[1]; r[6] = (__bf16)b[2]; r[7] = (__bf16)b[3];
  return r;
}
static __device__ __forceinline__ u32 pk2(float a, float b) {
  union { __bf16 h[2]; u32 w; } t;
  t.h[0] = (__bf16)a; t.h[1] = (__bf16)b;
  return t.w;
}

// ---- LDS layout (bytes) ----
// qk [64][392] bf16 : 0     .. 50176   (cols 0..191 q, 192..383 k, pad 8)
// vT [192][72] bf16 : 50176 .. 77824   ((h*32+d) x m, pad 8)
// ao [64][200] bf16 : alias over qk region after attention (q/k dead)
// 76 KB -> 2 blocks/CU (152 KB of 160 KB)
#define LDS_BYTES 77824

__global__ void __launch_bounds__(512, 4)
wattn_fused(const float* __restrict__ x, const float* __restrict__ mask,
            const float* __restrict__ qkv_w, const float* __restrict__ qkv_b,
            const float* __restrict__ proj_w, const float* __restrict__ proj_b,
            float* __restrict__ out)
{
  extern __shared__ char smem[];
  __bf16* qk = (__bf16*)smem;             // [64][392]
  __bf16* vT = (__bf16*)(smem + 50176);   // [192][72]
  __bf16* ao = (__bf16*)smem;             // [64][200] alias

  const int b    = blockIdx.x;
  const int tid  = threadIdx.x;
  const int wv   = tid >> 6;
  const int lane = tid & 63;
  const int r16  = lane & 15;
  const int q4   = lane >> 4;

  const float* xg = x + (size_t)b * (NTOK * CDIM);

  // ---------------- Phase A: QKV = x @ qkv_w^T + qkv_b ----------------
  // wave: rt = wv&3 (16-row tile), 18 col-tiles starting at (wv>>2)*18.
  // A and B fragments loaded f32 directly from global (x L2-resident, weights L2-hot).
  {
    const int rt = wv & 3;
    const int c0 = (wv >> 2) * 18;
    f32x4 acc[18];
#pragma unroll
    for (int i = 0; i < 18; ++i) acc[i] = (f32x4){0.f, 0.f, 0.f, 0.f};

    for (int k = 0; k < 6; ++k) {
      const float* ap = xg + (rt * 16 + r16) * 192 + k * 32 + q4 * 8;
      bfx8 af = pack8(*(const f32x4*)ap, *(const f32x4*)(ap + 4));
#pragma unroll
      for (int i = 0; i < 18; ++i) {
        const float* wp = qkv_w + (size_t)((c0 + i) * 16 + r16) * 192 + k * 32 + q4 * 8;
        bfx8 bf = pack8(*(const f32x4*)wp, *(const f32x4*)(wp + 4));
        acc[i] = __builtin_amdgcn_mfma_f32_16x16x32_bf16(af, bf, acc[i], 0, 0, 0);
      }
    }
    // epilogue: bias + convert; q/k row-major, v transposed
#pragma unroll
    for (int i = 0; i < 18; ++i) {
      const int ct = c0 + i;
      const float bias = qkv_b[ct * 16 + r16];
      if (ct < 24) {
#pragma unroll
        for (int r = 0; r < 4; ++r)
          qk[(rt * 16 + q4 * 4 + r) * 392 + ct * 16 + r16] =
              (__bf16)(acc[i][r] + bias);
      } else {
        const int hh = (ct - 24) >> 1;
        const int d  = ((ct - 24) & 1) * 16 + r16;
        bfx4 p;
#pragma unroll
        for (int r = 0; r < 4; ++r) p[r] = (__bf16)(acc[i][r] + bias);
        *(bfx4*)(vT + (hh * 32 + d) * 72 + rt * 16 + q4 * 4) = p;
      }
    }
  }
  __syncthreads();

  // ---------------- Phase B: attention, barrier-free ----------------
  // wave: nt = wv&3 (16 queries), heads h = 2*hp + (wv>>2), hp=0..2.
  // Swapped QK^T: S^T = mfma(K, Q) -> lane holds S[n=r16(+16nt)][m=16mt+4*q4+r].
  // Softmax per query-row across 4 lanes {n,n+16,n+32,n+48} via shfl_xor(16,32).
  // P redistributed to PV A-frag via 16 shuffles + selects; O kept in regs.
  const int wmask = b & (NWIN - 1);
  const int nt = wv & 3;
  const int h0 = wv >> 2;
  const int srcA = r16 + ((lane & 16) << 1);  // 16*((2g)&3) + r16
  const int srcB = srcA + 16;                 // 16*((2g+1)&3) + r16
  const bool hiT = (lane & 32) != 0;          // tile-select: g>=2 uses odd tile
  f32x4 o[3][2];
#pragma unroll
  for (int hp = 0; hp < 3; ++hp)
#pragma unroll
    for (int dt = 0; dt < 2; ++dt) o[hp][dt] = (f32x4){0.f, 0.f, 0.f, 0.f};

#pragma unroll
  for (int hp = 0; hp < 3; ++hp) {
    const int h = 2 * hp + h0;
    // Q as B-frag (row-major read), K as A-frag (row-major read)
    bfx8 qb = *(const bfx8*)(qk + (nt * 16 + r16) * 392 + h * 32 + q4 * 8);
    f32x4 st[4];
#pragma unroll
    for (int mt = 0; mt < 4; ++mt) {
      bfx8 ka = *(const bfx8*)(qk + (mt * 16 + r16) * 392 + 192 + h * 32 + q4 * 8);
      st[mt] = __builtin_amdgcn_mfma_f32_16x16x32_bf16(
          ka, qb, (f32x4){0.f, 0.f, 0.f, 0.f}, 0, 0, 0);
    }
    // logits: scale + mask ; lane's (n,m): n = nt*16+r16, m = mt*16 + q4*4 + r
    float lg[16];
    const float* mrow = mask + ((size_t)wmask * 64 + nt * 16 + r16) * 64 + q4 * 4;
#pragma unroll
    for (int mt = 0; mt < 4; ++mt) {
      f32x4 mk = *(const f32x4*)(mrow + mt * 16);
#pragma unroll
      for (int r = 0; r < 4; ++r) lg[mt * 4 + r] = st[mt][r] * SCALE + mk[r];
    }
    float mx = lg[0];
#pragma unroll
    for (int i2 = 1; i2 < 16; ++i2) mx = fmaxf(mx, lg[i2]);
    mx = fmaxf(mx, __shfl_xor(mx, 16));
    mx = fmaxf(mx, __shfl_xor(mx, 32));
    float sum = 0.f;
#pragma unroll
    for (int i2 = 0; i2 < 16; ++i2) { lg[i2] = __expf(lg[i2] - mx); sum += lg[i2]; }
    sum += __shfl_xor(sum, 16);
    sum += __shfl_xor(sum, 32);
    const float inv = 1.f / sum;
    // pack P to bf16 pairs: u[mt][0]=(m:+0,+1) u[mt][1]=(m:+2,+3) at m=16mt+4g
    u32 u[4][2];
#pragma unroll
    for (int mt = 0; mt < 4; ++mt) {
      u[mt][0] = pk2(lg[mt * 4 + 0] * inv, lg[mt * 4 + 1] * inv);
      u[mt][1] = pk2(lg[mt * 4 + 2] * inv, lg[mt * 4 + 3] * inv);
    }
    // redistribute to A-frag (lane g needs m = 32kk + 8g + j) and do PV
#pragma unroll
    for (int kk = 0; kk < 2; ++kk) {
      const int a0l = __shfl((int)u[kk * 2][0],     srcA, 64);
      const int a1l = __shfl((int)u[kk * 2][1],     srcA, 64);
      const int a0h = __shfl((int)u[kk * 2 + 1][0], srcA, 64);
      const int a1h = __shfl((int)u[kk * 2 + 1][1], srcA, 64);
      const int b0l = __shfl((int)u[kk * 2][0],     srcB, 64);
      const int b1l = __shfl((int)u[kk * 2][1],     srcB, 64);
      const int b0h = __shfl((int)u[kk * 2 + 1][0], srcB, 64);
      const int b1h = __shfl((int)u[kk * 2 + 1][1], srcB, 64);
      PAu pa;
      pa.w[0] = (u32)(hiT ? a0h : a0l);
      pa.w[1] = (u32)(hiT ? a1h : a1l);
      pa.w[2] = (u32)(hiT ? b0h : b0l);
      pa.w[3] = (u32)(hiT ? b1h : b1l);
#pragma unroll
      for (int dt = 0; dt < 2; ++dt) {
        bfx8 vb = *(const bfx8*)(vT + (h * 32 + dt * 16 + r16) * 72 + kk * 32 + q4 * 8);
        o[hp][dt] = __builtin_amdgcn_mfma_f32_16x16x32_bf16(pa.v, vb, o[hp][dt], 0, 0, 0);
      }
    }
  }
  __syncthreads();   // all q/k/vT reads done -> safe to alias ao over qk
  // write attention output [n][h*32+d] bf16
#pragma unroll
  for (int hp = 0; hp < 3; ++hp) {
    const int h = 2 * hp + h0;
#pragma unroll
    for (int dt = 0; dt < 2; ++dt)
#pragma unroll
      for (int r = 0; r < 4; ++r)
        ao[(nt * 16 + q4 * 4 + r) * 200 + h * 32 + dt * 16 + r16] =
            (__bf16)o[hp][dt][r];
  }
  __syncthreads();

  // ---------------- Phase C: out = ao @ proj_w^T + proj_b ----------------
  {
    f32x4 acc[3][2];
#pragma unroll
    for (int u2 = 0; u2 < 3; ++u2)
#pragma unroll
      for (int j = 0; j < 2; ++j) acc[u2][j] = (f32x4){0.f, 0.f, 0.f, 0.f};

    for (int k = 0; k < 6; ++k) {
#pragma unroll
      for (int u2 = 0; u2 < 3; ++u2) {
        const int uid  = wv + u2 * 8;      // 0..23
        const int ct   = uid % 12;
        const int half = uid / 12;
        const float* wp = proj_w + (size_t)(ct * 16 + r16) * 192 + k * 32 + q4 * 8;
        bfx8 bf = pack8(*(const f32x4*)wp, *(const f32x4*)(wp + 4));
#pragma unroll
        for (int j = 0; j < 2; ++j) {
          const int rt = half * 2 + j;
          bfx8 af = *(const bfx8*)(ao + (rt * 16 + r16) * 200 + k * 32 + q4 * 8);
          acc[u2][j] = __builtin_amdgcn_mfma_f32_16x16x32_bf16(af, bf, acc[u2][j], 0, 0, 0);
        }
      }
    }
    float* og = out + (size_t)b * (NTOK * CDIM);
#pragma unroll
    for (int u2 = 0; u2 < 3; ++u2) {
      const int uid  = wv + u2 * 8;
      const int ct   = uid % 12;
      const int half = uid / 12;
      const float bias = proj_b[ct * 16 + r16];
#pragma unroll
      for (int j = 0; j < 2; ++j) {
        const int rt = half * 2 + j;
#pragma unroll
        for (int r = 0; r < 4; ++r)
          og[(rt * 16 + q4 * 4 + r) * 192 + ct * 16 + r16] = acc[u2][j][r] + bias;
      }
    }
  }
}

extern "C" void kernel_launch(void* const* d_in, const int* in_sizes, int n_in,
                              void* d_out, int out_size, void* d_ws, size_t ws_size,
                              hipStream_t stream) {
  (void)in_sizes; (void)n_in; (void)d_ws; (void)ws_size; (void)out_size;
  const float* x      = (const float*)d_in[0];
  const float* mask   = (const float*)d_in[1];
  const float* qkv_w  = (const float*)d_in[2];
  const float* qkv_b  = (const float*)d_in[3];
  const float* proj_w = (const float*)d_in[4];
  const float* proj_b = (const float*)d_in[5];
  float* out = (float*)d_out;

  hipFuncSetAttribute((const void*)wattn_fused,
                      hipFuncAttributeMaxDynamicSharedMemorySize, LDS_BYTES);
  wattn_fused<<<dim3(4096), dim3(512), LDS_BYTES, stream>>>(
      x, mask, qkv_w, qkv_b, proj_w, proj_b, out);
}